// Round 3
// baseline (6623.689 us; speedup 1.0000x reference)
//
#include <hip/hip_runtime.h>

typedef unsigned short u16;
#define DEV __device__ __forceinline__

constexpr int B_  = 32768;
constexpr int S_  = 8;
constexpr int DK_ = 512;
constexpr int D_  = 64;
constexpr int H_  = 4;
constexpr int DH_ = 256;
constexpr int L_  = 4;
constexpr float SCALE_ = 0.125f;   // 1/sqrt(64)
constexpr float EPS_   = 1e-5f;

DEV float wsum(float x){
    #pragma unroll
    for (int m=1; m<64; m<<=1) x += __shfl_xor(x, m, 64);
    return x;
}

struct P {
    const float *query,*latent,*W1,*b1,*Wq,*bq,*Wk,*bk,*Wv,*bv,*Wo,*bo,
                *fW1,*fb1,*fW2,*fb2,*g1,*be1,*g2,*be2,
                *cWq,*cbq,*cWk,*cbk,*cWv,*cbv,*cWo,*cbo,*Wc,*bc,*Ws,*bs;
    float *o_color,*o_sigma,*o_out,*o_attn;
};

// per-wave LDS floats: so(512) + bufA(2080) + bufK(2080) + bufP(256)
constexpr int WLDS = 512 + 2080 + 2080 + 256;   // 4928 floats (19712 B, 16B-aligned)

__global__ __launch_bounds__(128) void rt_fused(P p){
    __shared__ float sh[2*WLDS];
    const int wave = threadIdx.x >> 6;
    const int lane = threadIdx.x & 63;
    const int b    = blockIdx.x*2 + wave;
    float* so   = sh + wave*WLDS;   // 512   : out staging [8][64]
    float* bufA = so   + 512;       // 2080  : Q stage [4][8][65] / concat [8][256]
    float* bufK = bufA + 2080;      // 2080  : K stage [4][8][65] / ffh [8][64]
    float* bufP = bufK + 2080;      // 256   : probs [4][64] / query [64]

    // ---------- embed: out = relu(latent @ W1 + b1) ----------
    float o[8];
    {
        float* lat = so;   // 4096 floats spanning so+bufA+bufK (4672 avail)
        const float4* latv = (const float4*)(p.latent + (size_t)b*(S_*DK_));
        float4* lat4 = (float4*)lat;
        #pragma unroll
        for (int k=0;k<16;++k) lat4[k*64+lane] = latv[k*64+lane];
        __syncthreads();
        float acc[8];
        #pragma unroll
        for (int s=0;s<8;++s) acc[s] = p.b1[lane];
        #pragma unroll 4
        for (int c=0;c<512;++c){
            float w = p.W1[c*64 + lane];
            #pragma unroll
            for (int s=0;s<8;++s) acc[s] = fmaf(lat[s*512+c], w, acc[s]);
        }
        #pragma unroll
        for (int s=0;s<8;++s) o[s] = fmaxf(acc[s], 0.f);
        __syncthreads();
    }

    // ---------- transformer layers ----------
    float v[4][8];
    for (int i=0;i<L_;++i){
        const float* Wq_i = p.Wq + (size_t)i*D_*DH_;
        const float* Wk_i = p.Wk + (size_t)i*D_*DH_;
        const float* Wv_i = p.Wv + (size_t)i*D_*DH_;
        const float* bq_i = p.bq + i*DH_;
        const float* bk_i = p.bk + i*DH_;
        const float* bv_i = p.bv + i*DH_;
        const float* Wo_i = p.Wo + (size_t)i*DH_*D_;
        const float* bo_i = p.bo + i*D_;
        const float* fW1_i= p.fW1+ i*D_*D_;
        const float* fb1_i= p.fb1+ i*D_;
        const float* fW2_i= p.fW2+ i*D_*D_;
        const float* fb2_i= p.fb2+ i*D_;
        const float* g1_i = p.g1 + i*D_;
        const float* be1_i= p.be1+ i*D_;
        const float* g2_i = p.g2 + i*D_;
        const float* be2_i= p.be2+ i*D_;

        #pragma unroll
        for (int s=0;s<8;++s) so[s*64+lane] = o[s];
        __syncthreads();

        // QKV projections: Q,K -> LDS (stride 65), V -> regs
        for (int h=0;h<4;++h){
            float aq[8], ak[8], av[8];
            float bqv = bq_i[h*64+lane], bkv = bk_i[h*64+lane], bvv = bv_i[h*64+lane];
            #pragma unroll
            for (int s=0;s<8;++s){ aq[s]=bqv; ak[s]=bkv; av[s]=bvv; }
            #pragma unroll 4
            for (int c=0;c<64;++c){
                int wi = c*256 + h*64 + lane;
                float wq=Wq_i[wi], wk=Wk_i[wi], wv=Wv_i[wi];
                #pragma unroll
                for (int s=0;s<8;++s){
                    float ov = so[s*64+c];
                    aq[s]=fmaf(ov,wq,aq[s]); ak[s]=fmaf(ov,wk,ak[s]); av[s]=fmaf(ov,wv,av[s]);
                }
            }
            #pragma unroll
            for (int s=0;s<8;++s){
                bufA[(h*8+s)*65+lane]=aq[s];
                bufK[(h*8+s)*65+lane]=ak[s];
                v[h][s]=av[s];
            }
        }
        __syncthreads();

        // scores + softmax (lane: q=lane>>3, k=lane&7) + attn output write
        {
            const int q = lane>>3, kk = lane&7;
            #pragma unroll
            for (int h=0;h<4;++h){
                float sc=0.f;
                #pragma unroll 8
                for (int d=0;d<64;++d) sc = fmaf(bufA[(h*8+q)*65+d], bufK[(h*8+kk)*65+d], sc);
                sc *= SCALE_;
                float mx = sc;
                mx=fmaxf(mx,__shfl_xor(mx,1,64));
                mx=fmaxf(mx,__shfl_xor(mx,2,64));
                mx=fmaxf(mx,__shfl_xor(mx,4,64));
                float e=__expf(sc-mx);
                float sm=e;
                sm+=__shfl_xor(sm,1,64); sm+=__shfl_xor(sm,2,64); sm+=__shfl_xor(sm,4,64);
                float pr=e/sm;
                p.o_attn[(size_t)b*1024 + i*256 + h*64 + lane] = pr;
                bufP[h*64+lane]=pr;
            }
        }
        __syncthreads();

        // PV: concat[s][h*64+d] -> bufA
        #pragma unroll
        for (int h=0;h<4;++h){
            #pragma unroll
            for (int s=0;s<8;++s){
                float acc=0.f;
                #pragma unroll
                for (int k2=0;k2<8;++k2) acc = fmaf(bufP[h*64+s*8+k2], v[h][k2], acc);
                bufA[s*256 + h*64 + lane] = acc;
            }
        }
        __syncthreads();

        // Wo projection + residual + LN1
        {
            float acc[8];
            float bv2 = bo_i[lane];
            #pragma unroll
            for (int s=0;s<8;++s) acc[s]=bv2;
            #pragma unroll 4
            for (int p2=0;p2<256;++p2){
                float w = Wo_i[p2*64 + lane];
                #pragma unroll
                for (int s=0;s<8;++s) acc[s]=fmaf(bufA[s*256+p2], w, acc[s]);
            }
            float g=g1_i[lane], be=be1_i[lane];
            #pragma unroll
            for (int s=0;s<8;++s){
                float x = acc[s] + o[s];
                float m = wsum(x)*(1.f/64.f);
                float xm = x-m;
                float var = wsum(xm*xm)*(1.f/64.f);
                o[s] = xm*rsqrtf(var+EPS_)*g + be;
            }
        }
        __syncthreads();

        // FF: relu(out@fW1+fb1)@fW2+fb2, residual + LN2
        #pragma unroll
        for (int s=0;s<8;++s) so[s*64+lane]=o[s];
        __syncthreads();
        {
            float acc[8];
            float bv2=fb1_i[lane];
            #pragma unroll
            for (int s=0;s<8;++s) acc[s]=bv2;
            #pragma unroll 4
            for (int c=0;c<64;++c){
                float w=fW1_i[c*64+lane];
                #pragma unroll
                for (int s=0;s<8;++s) acc[s]=fmaf(so[s*64+c], w, acc[s]);
            }
            #pragma unroll
            for (int s=0;s<8;++s) bufK[s*64+lane]=fmaxf(acc[s],0.f);
        }
        __syncthreads();
        {
            float acc[8];
            float bv2=fb2_i[lane];
            #pragma unroll
            for (int s=0;s<8;++s) acc[s]=bv2;
            #pragma unroll 4
            for (int c=0;c<64;++c){
                float w=fW2_i[c*64+lane];
                #pragma unroll
                for (int s=0;s<8;++s) acc[s]=fmaf(bufK[s*64+c], w, acc[s]);
            }
            float g=g2_i[lane], be=be2_i[lane];
            #pragma unroll
            for (int s=0;s<8;++s){
                float x = acc[s]+o[s];
                float m=wsum(x)*(1.f/64.f);
                float xm=x-m;
                float var=wsum(xm*xm)*(1.f/64.f);
                o[s]=xm*rsqrtf(var+EPS_)*g+be;
            }
        }
        __syncthreads();
    }

    // ---------- out output ----------
    #pragma unroll
    for (int s=0;s<8;++s) p.o_out[(size_t)b*512 + s*64 + lane] = o[s];

    // ---------- sigma ----------
    {
        float mx=o[0];
        #pragma unroll
        for (int s=1;s<8;++s) mx=fmaxf(mx,o[s]);
        float part = mx*p.Ws[lane];
        float sg = wsum(part) + p.bs[0];
        if (lane==0) p.o_sigma[b]=sg;
    }

    // ---------- cross attention ----------
    #pragma unroll
    for (int s=0;s<8;++s) so[s*64+lane]=o[s];
    bufP[lane]=p.query[(size_t)b*64 + lane];
    __syncthreads();

    float vc[4][8];
    for (int h=0;h<4;++h){
        {   // Qc (single query row)
            float aq=p.cbq[h*64+lane];
            #pragma unroll 4
            for (int c=0;c<64;++c) aq=fmaf(bufP[c], p.cWq[c*256 + h*64+lane], aq);
            bufA[h*65+lane]=aq;
        }
        float ak[8], av[8];
        float bkv=p.cbk[h*64+lane], bvv=p.cbv[h*64+lane];
        #pragma unroll
        for (int s=0;s<8;++s){ ak[s]=bkv; av[s]=bvv; }
        #pragma unroll 4
        for (int c=0;c<64;++c){
            int wi=c*256+h*64+lane;
            float wk=p.cWk[wi], wv=p.cWv[wi];
            #pragma unroll
            for (int s=0;s<8;++s){
                float ov=so[s*64+c];
                ak[s]=fmaf(ov,wk,ak[s]); av[s]=fmaf(ov,wv,av[s]);
            }
        }
        #pragma unroll
        for (int s=0;s<8;++s){ bufK[(h*8+s)*65+lane]=ak[s]; vc[h][s]=av[s]; }
    }
    __syncthreads();

    // scores + softmax (lanes 32..63 duplicate heads, keeps wave converged)
    {
        const int hh=(lane>>3)&3, k2=lane&7;
        float sc=0.f;
        #pragma unroll 8
        for (int d=0;d<64;++d) sc=fmaf(bufA[hh*65+d], bufK[(hh*8+k2)*65+d], sc);
        sc*=SCALE_;
        float mx=sc;
        mx=fmaxf(mx,__shfl_xor(mx,1,64));
        mx=fmaxf(mx,__shfl_xor(mx,2,64));
        mx=fmaxf(mx,__shfl_xor(mx,4,64));
        float e=__expf(sc-mx);
        float sm=e;
        sm+=__shfl_xor(sm,1,64); sm+=__shfl_xor(sm,2,64); sm+=__shfl_xor(sm,4,64);
        float pr=e/sm;
        if (lane<32) bufP[lane]=pr;
    }
    __syncthreads();

    // PV -> concat co[256] in bufA
    #pragma unroll
    for (int h=0;h<4;++h){
        float acc=0.f;
        #pragma unroll
        for (int k2=0;k2<8;++k2) acc=fmaf(bufP[h*8+k2], vc[h][k2], acc);
        bufA[h*64+lane]=acc;
    }
    __syncthreads();

    // cWo + relu + color head
    {
        float acc=p.cbo[lane];
        #pragma unroll 4
        for (int p2=0;p2<256;++p2) acc=fmaf(bufA[p2], p.cWo[p2*64+lane], acc);
        float r=fmaxf(acc,0.f);
        float c0=wsum(r*p.Wc[lane*3+0]);
        float c1=wsum(r*p.Wc[lane*3+1]);
        float c2=wsum(r*p.Wc[lane*3+2]);
        if (lane==0){
            p.o_color[(size_t)b*3+0]=c0+p.bc[0];
            p.o_color[(size_t)b*3+1]=c1+p.bc[1];
            p.o_color[(size_t)b*3+2]=c2+p.bc[2];
        }
    }
}

extern "C" void kernel_launch(void* const* d_in, const int* in_sizes, int n_in,
                              void* d_out, int out_size, void* d_ws, size_t ws_size,
                              hipStream_t stream){
    const float* const* ins = (const float* const*)d_in;
    P p;
    p.query=ins[0];  p.latent=ins[1]; p.W1=ins[2];   p.b1=ins[3];
    p.Wq=ins[4];     p.bq=ins[5];     p.Wk=ins[6];   p.bk=ins[7];
    p.Wv=ins[8];     p.bv=ins[9];     p.Wo=ins[10];  p.bo=ins[11];
    p.fW1=ins[12];   p.fb1=ins[13];   p.fW2=ins[14]; p.fb2=ins[15];
    p.g1=ins[16];    p.be1=ins[17];   p.g2=ins[18];  p.be2=ins[19];
    p.cWq=ins[20];   p.cbq=ins[21];   p.cWk=ins[22]; p.cbk=ins[23];
    p.cWv=ins[24];   p.cbv=ins[25];   p.cWo=ins[26]; p.cbo=ins[27];
    p.Wc=ins[28];    p.bc=ins[29];    p.Ws=ins[30];  p.bs=ins[31];
    float* out=(float*)d_out;
    p.o_color = out;
    p.o_sigma = out + (size_t)B_*3;
    p.o_out   = out + (size_t)B_*4;
    p.o_attn  = out + (size_t)B_*4 + (size_t)B_*512;
    hipLaunchKernelGGL(rt_fused, dim3(B_/2), dim3(128), 0, stream, p);
}